// Round 1
// baseline (516.930 us; speedup 1.0000x reference)
//
#include <hip/hip_runtime.h>
#include <hip/hip_bf16.h>

#define NN 8192
#define FIN 256
#define FOUT 64
#define L2E 1.4426950408889634f
#define PADK 40   // LDS k-stride in shorts (32 data + 8 pad -> even bank spread)

typedef __attribute__((ext_vector_type(8))) short short8;
typedef __attribute__((ext_vector_type(4))) float f32x4;
typedef __attribute__((ext_vector_type(4))) int   iv4;

// Barrier with LDS-only drain: leaves vmcnt (global prefetch) in flight.
#define BAR() do { \
  __asm__ __volatile__("s_waitcnt lgkmcnt(0)" ::: "memory"); \
  __builtin_amdgcn_s_barrier(); \
  __asm__ __volatile__("" ::: "memory"); \
} while (0)

__device__ __forceinline__ unsigned short f2bf(float x){
  unsigned u = __float_as_uint(x);
  u += 0x7FFFu + ((u >> 16) & 1u);      // RTNE
  return (unsigned short)(u >> 16);
}

// ---- k_pm: matmul-only prep (converter pass ELIMINATED — k_attn now
// streams raw adj directly; same 256 MB crosses HBM either way, but we
// save the converter kernel time + 16 MB mask write/read + serialization).
__global__ __launch_bounds__(256) void k_pm(const float* __restrict__ h,
    const float* __restrict__ W, const float* __restrict__ a,
    unsigned short* __restrict__ WhT, float* __restrict__ fs,
    float* __restrict__ fd, unsigned* __restrict__ gmax_u){
  const int t = threadIdx.x;
  const int l = t & 63, wv = t >> 6;
  __shared__ float Ws[128*64];   // 32 KB: half of W (k-tiled)
  __shared__ float hs[8][128];
  const int rb = blockIdx.x * 8;          // 8 rows per block, 2 per wave
  float acc0 = 0.f, acc1 = 0.f;
  for (int half = 0; half < 2; ++half){
    if (half) __syncthreads();
    for (int i = t; i < 2048; i += 256)
      ((float4*)Ws)[i] = ((const float4*)W)[half*2048 + i];
    {
      int rr = t >> 5, cc = t & 31;
      ((float4*)&hs[rr][0])[cc] =
          *(const float4*)(h + (size_t)(rb+rr)*FIN + half*128 + cc*4);
    }
    __syncthreads();
    #pragma unroll 8
    for (int k = 0; k < 128; ++k){
      float wval = Ws[k*64 + l];           // lane l = output feature
      acc0 = fmaf(hs[wv*2+0][k], wval, acc0);
      acc1 = fmaf(hs[wv*2+1][k], wval, acc1);
    }
  }
  const int r0 = rb + wv*2, r1 = r0 + 1;
  float a1 = a[l], a2 = a[64 + l];
  float p0 = acc0*a1, q0 = acc0*a2, p1 = acc1*a1, q1 = acc1*a2;
  #pragma unroll
  for (int m = 1; m < 64; m <<= 1){
    p0 += __shfl_xor(p0, m); q0 += __shfl_xor(q0, m);
    p1 += __shfl_xor(p1, m); q1 += __shfl_xor(q1, m);
  }
  if (l == 0){
    fs[r0] = p0*L2E; fs[r1] = p1*L2E; fd[r0] = q0*L2E; fd[r1] = q1*L2E;
    atomicMax(gmax_u, __float_as_uint(q0*L2E + 64.0f));
    atomicMax(gmax_u, __float_as_uint(q1*L2E + 64.0f));
  }
  WhT[(size_t)l*NN + r0] = f2bf(acc0);
  WhT[(size_t)l*NN + r1] = f2bf(acc1);
}

// ---- k_attn: block = 64 i-rows x 1024-j kchunk. WhT+fd staged in LDS;
// adjacency read RAW (8 consecutive ints / thread / substep, two dwordx4,
// 2-substep register prefetch — loads stay in flight across BAR()).
__device__ __forceinline__ void attn_math(iv4 da, iv4 db, f32x4 fv0, f32x4 fv1,
    short8 w0, short8 w1, short8 w2, short8 w3,
    float fsrL, float mL, f32x4* acc, float& s0, float& s1){
  const float fv[8] = {fv0[0],fv0[1],fv0[2],fv0[3], fv1[0],fv1[1],fv1[2],fv1[3]};
  const int   dv[8] = {da.x,da.y,da.z,da.w, db.x,db.y,db.z,db.w};
  float w[8];
  #pragma unroll
  for (int j = 0; j < 8; ++j){
    float x  = fsrL + fv[j];                      // log2 domain
    float tt = fmaxf(x, 0.2f*x);                  // leaky_relu (scale-invariant)
    float e  = __builtin_amdgcn_exp2f(tt - mL);   // v_exp_f32
    w[j] = dv[j] ? e : 0.0f;                      // adjacency gate
  }
  s0 += (w[0]+w[2]) + (w[4]+w[6]);
  s1 += (w[1]+w[3]) + (w[5]+w[7]);
  short8 af;
  __hip_bfloat162* afp = (__hip_bfloat162*)&af;
  #pragma unroll
  for (int j = 0; j < 4; ++j)
    afp[j] = __float22bfloat162_rn(make_float2(w[2*j], w[2*j+1]));  // v_cvt_pk_bf16_f32
  acc[0] = __builtin_amdgcn_mfma_f32_16x16x32_bf16(af, w0, acc[0], 0,0,0);
  acc[1] = __builtin_amdgcn_mfma_f32_16x16x32_bf16(af, w1, acc[1], 0,0,0);
  acc[2] = __builtin_amdgcn_mfma_f32_16x16x32_bf16(af, w2, acc[2], 0,0,0);
  acc[3] = __builtin_amdgcn_mfma_f32_16x16x32_bf16(af, w3, acc[3], 0,0,0);
}

// Verified layouts (m89/m120): A[m=lane&15][k=(lane>>4)*8+j],
// B[k=(lane>>4)*8+j][n=lane&15], C col=lane&15 row=(lane>>4)*4+reg.
__global__ __launch_bounds__(256, 4) void k_attn(const int* __restrict__ adj,
    const unsigned short* __restrict__ WhT, const float* __restrict__ fs,
    const float* __restrict__ fd, const unsigned* __restrict__ gmax_u,
    float* __restrict__ acc_out, float* __restrict__ s_out){
  __shared__ unsigned short bslab[2][64*PADK];   // [buf][n][k]
  __shared__ float fslab[2][32];
  const int t = threadIdx.x, l = t & 63, wv = t >> 6;
  const int g = blockIdx.x & 127;        // 128 groups of 64 i-rows
  const int kchunk = blockIdx.x >> 7;    // 8 k-splits of 1024 j
  const int row = l & 15, quad = l >> 4;
  const int ibase = g*64 + wv*16;
  const int irow  = ibase + row;
  const float gmaxL = __uint_as_float(*gmax_u) - 64.0f;
  const float fsrL  = fs[irow];
  const float xL    = fsrL + gmaxL;
  const float mL    = fmaxf(xL, 0.2f*xL);  // row-max upper bound (leaky monotone)

  const unsigned jbase = (unsigned)kchunk*1024u;
  const unsigned sg_off = (unsigned)l*8192u + jbase + (unsigned)wv*8u;
  const int      sl_off = l*PADK + wv*8;
  const int      qsh    = quad*8;

  // raw adjacency: thread covers j = jbase + s*32 + qsh + {0..7}
  const iv4* __restrict__ ap =
      (const iv4*)(adj + (size_t)irow*8192u + jbase + (unsigned)qsh);
  // substep s -> ap[s*8], ap[s*8+1]   (byte stride 128/substep, 16-B aligned)

  f32x4 acc[4];
  #pragma unroll
  for (int nb = 0; nb < 4; ++nb) acc[nb] = (f32x4){0.f,0.f,0.f,0.f};

  // prologue: stage step 0 into buf 0; prefetch adj for substeps 0,1
  {
    short8 v = *(const short8*)(WhT + sg_off);
    *(short8*)&bslab[0][sl_off] = v;
    if (t < 32) fslab[0][t] = fd[jbase + t];
  }
  iv4 c0a = ap[0], c0b = ap[1];          // substep 0
  iv4 c1a = ap[8], c1b = ap[9];          // substep 1

  float s0 = 0.f, s1 = 0.f;
  short8 nw; float nf = 0.f;

  #pragma unroll 1
  for (int s = 0; s < 32; s += 2){
    // ---- even sub-step: consume buf0/c0, stage s+1 -> buf1
    BAR();
    nw = *(const short8*)(WhT + sg_off + (s+1)*32);
    if (t < 32) nf = fd[jbase + (s+1)*32 + t];
    {
      f32x4 fv0 = *(const f32x4*)&fslab[0][qsh];
      f32x4 fv1 = *(const f32x4*)&fslab[0][qsh + 4];
      short8 w0 = *(const short8*)&bslab[0][( 0 + row)*PADK + qsh];
      short8 w1 = *(const short8*)&bslab[0][(16 + row)*PADK + qsh];
      short8 w2 = *(const short8*)&bslab[0][(32 + row)*PADK + qsh];
      short8 w3 = *(const short8*)&bslab[0][(48 + row)*PADK + qsh];
      attn_math(c0a, c0b, fv0, fv1, w0, w1, w2, w3, fsrL, mL, acc, s0, s1);
    }
    if (s + 2 < 32){ c0a = ap[(s+2)*8]; c0b = ap[(s+2)*8 + 1]; }
    *(short8*)&bslab[1][sl_off] = nw;
    if (t < 32) fslab[1][t] = nf;

    // ---- odd sub-step: consume buf1/c1, stage s+2 -> buf0
    BAR();
    if (s + 2 < 32){
      nw = *(const short8*)(WhT + sg_off + (s+2)*32);
      if (t < 32) nf = fd[jbase + (s+2)*32 + t];
    }
    {
      f32x4 fv0 = *(const f32x4*)&fslab[1][qsh];
      f32x4 fv1 = *(const f32x4*)&fslab[1][qsh + 4];
      short8 w0 = *(const short8*)&bslab[1][( 0 + row)*PADK + qsh];
      short8 w1 = *(const short8*)&bslab[1][(16 + row)*PADK + qsh];
      short8 w2 = *(const short8*)&bslab[1][(32 + row)*PADK + qsh];
      short8 w3 = *(const short8*)&bslab[1][(48 + row)*PADK + qsh];
      attn_math(c1a, c1b, fv0, fv1, w0, w1, w2, w3, fsrL, mL, acc, s0, s1);
    }
    if (s + 3 < 32){ c1a = ap[(s+3)*8]; c1b = ap[(s+3)*8 + 1]; }
    if (s + 2 < 32){
      *(short8*)&bslab[0][sl_off] = nw;
      if (t < 32) fslab[0][t] = nf;
    }
  }

  float sacc = s0 + s1;
  sacc += __shfl_xor(sacc, 16);
  sacc += __shfl_xor(sacc, 32);
  if (l < 16) s_out[kchunk*NN + ibase + l] = sacc;
  float* op = acc_out + ((size_t)kchunk*NN + ibase)*FOUT;
  #pragma unroll
  for (int nb = 0; nb < 4; ++nb)
    #pragma unroll
    for (int r = 0; r < 4; ++r)
      op[(quad*4 + r)*FOUT + nb*16 + row] = acc[nb][r];
}

// ---- k_out: combine 8 split-K partials, normalize, ELU.
__global__ __launch_bounds__(256) void k_out(const float* __restrict__ acc,
    const float* __restrict__ s, float* __restrict__ out){
  const int idx = blockIdx.x*256 + threadIdx.x;   // 524288 total
  const int i = idx >> 6;
  float num = 0.f, den = 0.f;
  #pragma unroll
  for (int ks = 0; ks < 8; ++ks){
    num += acc[idx + (size_t)ks*(NN*FOUT)];
    den += s[i + ks*NN];
  }
  float x = num / den;
  out[idx] = (x > 0.f) ? x : (__expf(x) - 1.0f);
}

extern "C" void kernel_launch(void* const* d_in, const int* in_sizes, int n_in,
                              void* d_out, int out_size, void* d_ws, size_t ws_size,
                              hipStream_t stream){
  const float* h   = (const float*)d_in[0];
  const int*   adj = (const int*)d_in[1];
  const float* W   = (const float*)d_in[2];
  const float* a   = (const float*)d_in[3];
  char* ws = (char*)d_ws;
  // ws: [0,1M) WhT | 1M fs | +32K fd | +64K gmax | [2M,18M) acc x8 |
  //     [20M,+256K) s x8     (mask buffer eliminated)
  unsigned short* WhT = (unsigned short*)ws;
  float*    fs     = (float*)(ws + (1u<<20));
  float*    fd     = (float*)(ws + (1u<<20) + 32768);
  unsigned* gmax_u = (unsigned*)(ws + (1u<<20) + 65536);
  float*    acc    = (float*)(ws + (2u<<20));
  float*    s_ws   = (float*)(ws + (20u<<20));

  (void)hipMemsetAsync(gmax_u, 0, 4, stream);
  k_pm<<<1024, 256, 0, stream>>>(h, W, a, WhT, fs, fd, gmax_u);
  k_attn<<<1024, 256, 0, stream>>>(adj, WhT, fs, fd, gmax_u, acc, s_ws);
  k_out<<<2048, 256, 0, stream>>>(acc, s_ws, (float*)d_out);
}

// Round 2
// 512.551 us; speedup vs baseline: 1.0085x; 1.0085x over previous
//
#include <hip/hip_runtime.h>
#include <hip/hip_bf16.h>

#define NN 8192
#define FIN 256
#define FOUT 64
#define L2E 1.4426950408889634f

typedef __attribute__((ext_vector_type(8))) short short8;
typedef __attribute__((ext_vector_type(4))) float f32x4;
typedef __attribute__((ext_vector_type(4))) int   iv4;
typedef unsigned long long u64;

__device__ __forceinline__ unsigned short f2bf(float x){
  unsigned u = __float_as_uint(x);
  u += 0x7FFFu + ((u >> 16) & 1u);      // RTNE
  return (unsigned short)(u >> 16);
}

// ---- k_pm: matmul-only prep (verified R1).
__global__ __launch_bounds__(256) void k_pm(const float* __restrict__ h,
    const float* __restrict__ W, const float* __restrict__ a,
    unsigned short* __restrict__ WhT, float* __restrict__ fs,
    float* __restrict__ fd, unsigned* __restrict__ gmax_u){
  const int t = threadIdx.x;
  const int l = t & 63, wv = t >> 6;
  __shared__ float Ws[128*64];   // 32 KB: half of W (k-tiled)
  __shared__ float hs[8][128];
  const int rb = blockIdx.x * 8;          // 8 rows per block, 2 per wave
  float acc0 = 0.f, acc1 = 0.f;
  for (int half = 0; half < 2; ++half){
    if (half) __syncthreads();
    for (int i = t; i < 2048; i += 256)
      ((float4*)Ws)[i] = ((const float4*)W)[half*2048 + i];
    {
      int rr = t >> 5, cc = t & 31;
      ((float4*)&hs[rr][0])[cc] =
          *(const float4*)(h + (size_t)(rb+rr)*FIN + half*128 + cc*4);
    }
    __syncthreads();
    #pragma unroll 8
    for (int k = 0; k < 128; ++k){
      float wval = Ws[k*64 + l];           // lane l = output feature
      acc0 = fmaf(hs[wv*2+0][k], wval, acc0);
      acc1 = fmaf(hs[wv*2+1][k], wval, acc1);
    }
  }
  const int r0 = rb + wv*2, r1 = r0 + 1;
  float a1 = a[l], a2 = a[64 + l];
  float p0 = acc0*a1, q0 = acc0*a2, p1 = acc1*a1, q1 = acc1*a2;
  #pragma unroll
  for (int m = 1; m < 64; m <<= 1){
    p0 += __shfl_xor(p0, m); q0 += __shfl_xor(q0, m);
    p1 += __shfl_xor(p1, m); q1 += __shfl_xor(q1, m);
  }
  if (l == 0){
    fs[r0] = p0*L2E; fs[r1] = p1*L2E; fd[r0] = q0*L2E; fd[r1] = q1*L2E;
    atomicMax(gmax_u, __float_as_uint(q0*L2E + 64.0f));
    atomicMax(gmax_u, __float_as_uint(q1*L2E + 64.0f));
  }
  WhT[(size_t)l*NN + r0] = f2bf(acc0);
  WhT[(size_t)l*NN + r1] = f2bf(acc1);
}

// ballot one 1-KB adj row-group (row RR of the wave's 16); capture into the
// lanes whose consumer row matches. Bit lam of b_c <-> j_local = 4*lam + c.
__device__ __forceinline__ void balrow(iv4 P, int RR, int row,
    u64& B0, u64& B1, u64& B2, u64& B3){
  u64 b0 = __ballot(P.x != 0);
  u64 b1 = __ballot(P.y != 0);
  u64 b2 = __ballot(P.z != 0);
  u64 b3 = __ballot(P.w != 0);
  if (row == RR){ B0 = b0; B1 = b1; B2 = b2; B3 = b3; }
}

// attn math for 8 cells; gates from ballot extracts (g_c bit0 -> jj=c,
// bit1 -> jj=c+4, since j_local = ss*32 + quad*8 + jj = 4*lam + (jj&3),
// lam = ss*8 + quad*2 + (jj>>2)).
__device__ __forceinline__ void attn_math(unsigned g0, unsigned g1,
    unsigned g2, unsigned g3, f32x4 fv0, f32x4 fv1,
    short8 w0, short8 w1, short8 w2, short8 w3,
    float fsrL, float mL, f32x4* acc, float& s0, float& s1){
  const float fv[8] = {fv0[0],fv0[1],fv0[2],fv0[3], fv1[0],fv1[1],fv1[2],fv1[3]};
  const unsigned gb[8] = {g0&1u, g1&1u, g2&1u, g3&1u,
                          g0&2u, g1&2u, g2&2u, g3&2u};
  float w[8];
  #pragma unroll
  for (int j = 0; j < 8; ++j){
    float x  = fsrL + fv[j];                      // log2 domain
    float tt = fmaxf(x, 0.2f*x);                  // leaky_relu (scale-invariant)
    float e  = __builtin_amdgcn_exp2f(tt - mL);   // v_exp_f32
    w[j] = gb[j] ? e : 0.0f;                      // adjacency gate
  }
  s0 += (w[0]+w[2]) + (w[4]+w[6]);
  s1 += (w[1]+w[3]) + (w[5]+w[7]);
  short8 af;
  __hip_bfloat162* afp = (__hip_bfloat162*)&af;
  #pragma unroll
  for (int j = 0; j < 4; ++j)
    afp[j] = __float22bfloat162_rn(make_float2(w[2*j], w[2*j+1]));
  acc[0] = __builtin_amdgcn_mfma_f32_16x16x32_bf16(af, w0, acc[0], 0,0,0);
  acc[1] = __builtin_amdgcn_mfma_f32_16x16x32_bf16(af, w1, acc[1], 0,0,0);
  acc[2] = __builtin_amdgcn_mfma_f32_16x16x32_bf16(af, w2, acc[2], 0,0,0);
  acc[3] = __builtin_amdgcn_mfma_f32_16x16x32_bf16(af, w3, acc[3], 0,0,0);
}

// ---- k_attn: fused converter + attention. No LDS, no barriers; each wave
// independently owns 16 i-rows x 1024-j kchunk. adj streamed in m13 shape
// (whole-wave contiguous 1-KB dwordx4 per row, 8 KB/wave bursts), bits
// redistributed via ballot into per-thread u64 registers per 8-substep
// horizon. FIFO-safe: per-substep WhT/fd prefetch issued BEFORE adj bursts,
// so vmcnt waits on WhT never drain in-flight adj.
__global__ __launch_bounds__(256, 2) void k_attn(const int* __restrict__ adj,
    const unsigned short* __restrict__ WhT, const float* __restrict__ fs,
    const float* __restrict__ fd, const unsigned* __restrict__ gmax_u,
    float* __restrict__ acc_out, float* __restrict__ s_out){
  const int t = threadIdx.x, l = t & 63, wv = t >> 6;
  const int g = blockIdx.x & 127;        // 128 groups of 64 i-rows
  const int kchunk = blockIdx.x >> 7;    // 8 k-splits of 1024 j
  const int row = l & 15, quad = l >> 4;
  const int ibase = g*64 + wv*16;
  const int irow  = ibase + row;
  const float gmaxL = __uint_as_float(*gmax_u) - 64.0f;
  const float fsrL  = fs[irow];
  const float xL    = fsrL + gmaxL;
  const float mL    = fmaxf(xL, 0.2f*xL);  // row-max upper bound
  const unsigned jbase = (unsigned)kchunk*1024u;

  // adj: wave's 16 rows, lane-indexed iv4 (16 B). Row r, horizon h group:
  // aq[r*2048 + h*64]  (one whole-wave instruction = 1 KB contiguous).
  const iv4* __restrict__ aq =
      (const iv4*)(adj + (size_t)ibase*8192u + jbase) + l;
  // WhT fragment bases (feature-major); substep s at offset s*32 shorts.
  const unsigned short* __restrict__ wp0 = WhT + (size_t)( 0+row)*NN + jbase + quad*8;
  const unsigned short* __restrict__ wp1 = WhT + (size_t)(16+row)*NN + jbase + quad*8;
  const unsigned short* __restrict__ wp2 = WhT + (size_t)(32+row)*NN + jbase + quad*8;
  const unsigned short* __restrict__ wp3 = WhT + (size_t)(48+row)*NN + jbase + quad*8;
  const float* __restrict__ fp = fd + jbase + quad*8;

  f32x4 acc[4];
  #pragma unroll
  for (int nb = 0; nb < 4; ++nb) acc[nb] = (f32x4){0.f,0.f,0.f,0.f};

  u64 Bc0=0,Bc1=0,Bc2=0,Bc3=0, Bn0=0,Bn1=0,Bn2=0,Bn3=0;
  iv4 p0,p1,p2,p3,p4,p5,p6,p7;

  // ---- prologue: load+process horizon 0 (two 8-row halves)
  p0 = aq[0*2048]; p1 = aq[1*2048]; p2 = aq[2*2048]; p3 = aq[3*2048];
  p4 = aq[4*2048]; p5 = aq[5*2048]; p6 = aq[6*2048]; p7 = aq[7*2048];
  balrow(p0,0,row,Bc0,Bc1,Bc2,Bc3); balrow(p1,1,row,Bc0,Bc1,Bc2,Bc3);
  balrow(p2,2,row,Bc0,Bc1,Bc2,Bc3); balrow(p3,3,row,Bc0,Bc1,Bc2,Bc3);
  balrow(p4,4,row,Bc0,Bc1,Bc2,Bc3); balrow(p5,5,row,Bc0,Bc1,Bc2,Bc3);
  balrow(p6,6,row,Bc0,Bc1,Bc2,Bc3); balrow(p7,7,row,Bc0,Bc1,Bc2,Bc3);
  p0 = aq[ 8*2048]; p1 = aq[ 9*2048]; p2 = aq[10*2048]; p3 = aq[11*2048];
  p4 = aq[12*2048]; p5 = aq[13*2048]; p6 = aq[14*2048]; p7 = aq[15*2048];
  balrow(p0, 8,row,Bc0,Bc1,Bc2,Bc3); balrow(p1, 9,row,Bc0,Bc1,Bc2,Bc3);
  balrow(p2,10,row,Bc0,Bc1,Bc2,Bc3); balrow(p3,11,row,Bc0,Bc1,Bc2,Bc3);
  balrow(p4,12,row,Bc0,Bc1,Bc2,Bc3); balrow(p5,13,row,Bc0,Bc1,Bc2,Bc3);
  balrow(p6,14,row,Bc0,Bc1,Bc2,Bc3); balrow(p7,15,row,Bc0,Bc1,Bc2,Bc3);

  // prefetch substep 0 operands
  short8 wA = *(const short8*)(wp0);
  short8 wB = *(const short8*)(wp1);
  short8 wC = *(const short8*)(wp2);
  short8 wD = *(const short8*)(wp3);
  f32x4 fva = *(const f32x4*)(fp);
  f32x4 fvb = *(const f32x4*)(fp + 4);

  float s0 = 0.f, s1 = 0.f;

  #pragma unroll 1
  for (int h = 0; h < 4; ++h){
    const iv4* __restrict__ aqn = aq + (h+1)*64;   // next horizon groups
    #pragma unroll
    for (int ss = 0; ss < 8; ++ss){
      const int s = h*8 + ss;
      // 1) prefetch next substep's WhT/fd (issued BEFORE adj -> FIFO-safe)
      short8 nwA = wA, nwB = wB, nwC = wC, nwD = wD;
      f32x4 nfva = fva, nfvb = fvb;
      if (h < 3 || ss < 7){
        const int o = (s+1)*32;
        nwA = *(const short8*)(wp0 + o);
        nwB = *(const short8*)(wp1 + o);
        nwC = *(const short8*)(wp2 + o);
        nwD = *(const short8*)(wp3 + o);
        nfva = *(const f32x4*)(fp + o);
        nfvb = *(const f32x4*)(fp + o + 4);
      }
      // 2) adj burst for horizon h+1 (4 contiguous 1-KB rows per burst)
      if (h < 3){
        if (ss == 0){ p0=aqn[0*2048]; p1=aqn[1*2048]; p2=aqn[ 2*2048]; p3=aqn[ 3*2048]; }
        if (ss == 1){ p4=aqn[4*2048]; p5=aqn[5*2048]; p6=aqn[ 6*2048]; p7=aqn[ 7*2048]; }
        if (ss == 4){ p0=aqn[8*2048]; p1=aqn[9*2048]; p2=aqn[10*2048]; p3=aqn[11*2048]; }
        if (ss == 5){ p4=aqn[12*2048]; p5=aqn[13*2048]; p6=aqn[14*2048]; p7=aqn[15*2048]; }
      }
      // 3) gates from ballot registers, consume current operands
      {
        const int sh = ss*8 + quad*2;
        unsigned g0 = (unsigned)(Bc0 >> sh);
        unsigned g1 = (unsigned)(Bc1 >> sh);
        unsigned g2 = (unsigned)(Bc2 >> sh);
        unsigned g3 = (unsigned)(Bc3 >> sh);
        attn_math(g0,g1,g2,g3, fva,fvb, wA,wB,wC,wD, fsrL, mL, acc, s0, s1);
      }
      wA = nwA; wB = nwB; wC = nwC; wD = nwD; fva = nfva; fvb = nfvb;
      // 4) half-horizon ballot processing (>=2 substeps of load slack)
      if (h < 3 && ss == 3){
        balrow(p0,0,row,Bn0,Bn1,Bn2,Bn3); balrow(p1,1,row,Bn0,Bn1,Bn2,Bn3);
        balrow(p2,2,row,Bn0,Bn1,Bn2,Bn3); balrow(p3,3,row,Bn0,Bn1,Bn2,Bn3);
        balrow(p4,4,row,Bn0,Bn1,Bn2,Bn3); balrow(p5,5,row,Bn0,Bn1,Bn2,Bn3);
        balrow(p6,6,row,Bn0,Bn1,Bn2,Bn3); balrow(p7,7,row,Bn0,Bn1,Bn2,Bn3);
      }
      if (h < 3 && ss == 7){
        balrow(p0, 8,row,Bn0,Bn1,Bn2,Bn3); balrow(p1, 9,row,Bn0,Bn1,Bn2,Bn3);
        balrow(p2,10,row,Bn0,Bn1,Bn2,Bn3); balrow(p3,11,row,Bn0,Bn1,Bn2,Bn3);
        balrow(p4,12,row,Bn0,Bn1,Bn2,Bn3); balrow(p5,13,row,Bn0,Bn1,Bn2,Bn3);
        balrow(p6,14,row,Bn0,Bn1,Bn2,Bn3); balrow(p7,15,row,Bn0,Bn1,Bn2,Bn3);
        Bc0 = Bn0; Bc1 = Bn1; Bc2 = Bn2; Bc3 = Bn3;
      }
    }
  }

  float sacc = s0 + s1;
  sacc += __shfl_xor(sacc, 16);
  sacc += __shfl_xor(sacc, 32);
  if (l < 16) s_out[kchunk*NN + ibase + l] = sacc;
  float* op = acc_out + ((size_t)kchunk*NN + ibase)*FOUT;
  #pragma unroll
  for (int nb = 0; nb < 4; ++nb)
    #pragma unroll
    for (int r = 0; r < 4; ++r)
      op[(quad*4 + r)*FOUT + nb*16 + row] = acc[nb][r];
}

// ---- k_out: combine 8 split-K partials, normalize, ELU.
__global__ __launch_bounds__(256) void k_out(const float* __restrict__ acc,
    const float* __restrict__ s, float* __restrict__ out){
  const int idx = blockIdx.x*256 + threadIdx.x;   // 524288 total
  const int i = idx >> 6;
  float num = 0.f, den = 0.f;
  #pragma unroll
  for (int ks = 0; ks < 8; ++ks){
    num += acc[idx + (size_t)ks*(NN*FOUT)];
    den += s[i + ks*NN];
  }
  float x = num / den;
  out[idx] = (x > 0.f) ? x : (__expf(x) - 1.0f);
}

extern "C" void kernel_launch(void* const* d_in, const int* in_sizes, int n_in,
                              void* d_out, int out_size, void* d_ws, size_t ws_size,
                              hipStream_t stream){
  const float* h   = (const float*)d_in[0];
  const int*   adj = (const int*)d_in[1];
  const float* W   = (const float*)d_in[2];
  const float* a   = (const float*)d_in[3];
  char* ws = (char*)d_ws;
  // ws: [0,1M) WhT | 1M fs | +32K fd | +64K gmax | [2M,18M) acc x8 |
  //     [20M,+256K) s x8
  unsigned short* WhT = (unsigned short*)ws;
  float*    fs     = (float*)(ws + (1u<<20));
  float*    fd     = (float*)(ws + (1u<<20) + 32768);
  unsigned* gmax_u = (unsigned*)(ws + (1u<<20) + 65536);
  float*    acc    = (float*)(ws + (2u<<20));
  float*    s_ws   = (float*)(ws + (20u<<20));

  (void)hipMemsetAsync(gmax_u, 0, 4, stream);
  k_pm<<<1024, 256, 0, stream>>>(h, W, a, WhT, fs, fd, gmax_u);
  k_attn<<<1024, 256, 0, stream>>>(adj, WhT, fs, fd, gmax_u, acc, s_ws);
  k_out<<<2048, 256, 0, stream>>>(acc, s_ws, (float*)d_out);
}

// Round 3
// 432.862 us; speedup vs baseline: 1.1942x; 1.1841x over previous
//
#include <hip/hip_runtime.h>
#include <hip/hip_bf16.h>

#define NN 8192
#define FIN 256
#define FOUT 64
#define L2E 1.4426950408889634f
#define PADK2 72  // LDS k-stride in shorts (64 data + 8 pad -> 2-way max bank alias)

typedef __attribute__((ext_vector_type(8))) short short8;
typedef __attribute__((ext_vector_type(4))) float f32x4;
typedef __attribute__((ext_vector_type(4))) int   iv4;

// Barrier with LDS-only drain: leaves vmcnt (global prefetch) in flight.
#define BAR() do { \
  __asm__ __volatile__("s_waitcnt lgkmcnt(0)" ::: "memory"); \
  __builtin_amdgcn_s_barrier(); \
  __asm__ __volatile__("" ::: "memory"); \
} while (0)

__device__ __forceinline__ unsigned short f2bf(float x){
  unsigned u = __float_as_uint(x);
  u += 0x7FFFu + ((u >> 16) & 1u);      // RTNE
  return (unsigned short)(u >> 16);
}

// spread4: deposit bit i of 8-bit x at bit 4i (verified: 0x02 -> 0x10).
__device__ __forceinline__ unsigned spread4(unsigned x){
  x &= 0xFFu;
  x = (x | (x << 12)) & 0x000F000Fu;
  x = (x | (x << 6))  & 0x03030303u;
  x = (x | (x << 3))  & 0x11111111u;
  return x;
}

// Convert one 1-KB group (256 j, lane l holds j = g*256 + 4l + c, c=0..3) to
// 8 mask words (j-order). All lanes redundantly compute word (l&7);
// lanes 0-7 store (one 32-B coalesced store).
__device__ __forceinline__ void cv_process(iv4 d, int l,
                                           unsigned* __restrict__ mp, int g){
  unsigned n = (unsigned)(d.x != 0)        | ((unsigned)(d.y != 0) << 1)
             | ((unsigned)(d.z != 0) << 2) | ((unsigned)(d.w != 0) << 3);
  unsigned long long B0 = __ballot((n & 1u) != 0);   // bit l <-> j = 4l+0
  unsigned long long B1 = __ballot((n & 2u) != 0);   // j = 4l+1
  unsigned long long B2 = __ballot((n & 4u) != 0);   // j = 4l+2
  unsigned long long B3 = __ballot((n & 8u) != 0);   // j = 4l+3
  const int hi = l & 4, sh = (l & 3) * 8;            // byte (l&7) of each u64
  unsigned b0 = (unsigned)((hi ? (B0 >> 32) : B0) >> sh);
  unsigned b1 = (unsigned)((hi ? (B1 >> 32) : B1) >> sh);
  unsigned b2 = (unsigned)((hi ? (B2 >> 32) : B2) >> sh);
  unsigned b3 = (unsigned)((hi ? (B3 >> 32) : B3) >> sh);
  unsigned word = spread4(b0) | (spread4(b1) << 1)
                | (spread4(b2) << 2) | (spread4(b3) << 3);
  if (l < 8) mp[g*8 + l] = word;   // word w covers j [g*256+w*32, +32)
}

// ---- k_pm: heterogeneous fused kernel (R0-verified), bid%3 interleave so
// BW-bound converter blocks co-schedule with VALU/LDS-bound prep blocks.
__global__ __launch_bounds__(256) void k_pm(const float* __restrict__ h,
    const float* __restrict__ W, const float* __restrict__ a,
    const int* __restrict__ adj, unsigned short* __restrict__ WhT,
    float* __restrict__ fs, float* __restrict__ fd,
    unsigned* __restrict__ gmax_u, unsigned* __restrict__ mask){
  const int bid = blockIdx.x, t = threadIdx.x;
  const int l = t & 63, wv = t >> 6;
  if (bid % 3 == 0){
    const int pid = bid / 3;                // 0..1023
    __shared__ float Ws[128*64];   // 32 KB: half of W (k-tiled)
    __shared__ float hs[8][128];
    const int rb = pid * 8;                 // 8 rows per block, 2 per wave
    float acc0 = 0.f, acc1 = 0.f;
    for (int half = 0; half < 2; ++half){
      if (half) __syncthreads();
      for (int i = t; i < 2048; i += 256)
        ((float4*)Ws)[i] = ((const float4*)W)[half*2048 + i];
      {
        int rr = t >> 5, cc = t & 31;
        ((float4*)&hs[rr][0])[cc] =
            *(const float4*)(h + (size_t)(rb+rr)*FIN + half*128 + cc*4);
      }
      __syncthreads();
      #pragma unroll 8
      for (int k = 0; k < 128; ++k){
        float wval = Ws[k*64 + l];           // lane l = output feature
        acc0 = fmaf(hs[wv*2+0][k], wval, acc0);
        acc1 = fmaf(hs[wv*2+1][k], wval, acc1);
      }
    }
    const int r0 = rb + wv*2, r1 = r0 + 1;
    float a1 = a[l], a2 = a[64 + l];
    float p0 = acc0*a1, q0 = acc0*a2, p1 = acc1*a1, q1 = acc1*a2;
    #pragma unroll
    for (int m = 1; m < 64; m <<= 1){
      p0 += __shfl_xor(p0, m); q0 += __shfl_xor(q0, m);
      p1 += __shfl_xor(p1, m); q1 += __shfl_xor(q1, m);
    }
    if (l == 0){
      fs[r0] = p0*L2E; fs[r1] = p1*L2E; fd[r0] = q0*L2E; fd[r1] = q1*L2E;
      atomicMax(gmax_u, __float_as_uint(q0*L2E + 64.0f));
      atomicMax(gmax_u, __float_as_uint(q1*L2E + 64.0f));
    }
    WhT[(size_t)l*NN + r0] = f2bf(acc0);
    WhT[(size_t)l*NN + r1] = f2bf(acc1);
  } else {
    const int cid = bid - bid/3 - 1;        // 0..2047
    const unsigned rowid = (unsigned)cid*4u + (unsigned)wv;  // 0..8191
    const iv4* __restrict__ ap = (const iv4*)(adj + (size_t)rowid*8192u) + l;
    unsigned* __restrict__ mp = mask + rowid*256u;
    // 32 groups of 256 j; 8 x 1-KB loads in flight (named regs, 8 KB/wave)
    iv4 d0 = ap[0*64], d1 = ap[1*64], d2 = ap[2*64], d3 = ap[3*64];
    iv4 d4 = ap[4*64], d5 = ap[5*64], d6 = ap[6*64], d7 = ap[7*64];
    #pragma unroll 1
    for (int i = 0; i < 32; i += 8){
      cv_process(d0, l, mp, i+0); if (i+ 8 < 32) d0 = ap[(i+ 8)*64];
      cv_process(d1, l, mp, i+1); if (i+ 9 < 32) d1 = ap[(i+ 9)*64];
      cv_process(d2, l, mp, i+2); if (i+10 < 32) d2 = ap[(i+10)*64];
      cv_process(d3, l, mp, i+3); if (i+11 < 32) d3 = ap[(i+11)*64];
      cv_process(d4, l, mp, i+4); if (i+12 < 32) d4 = ap[(i+12)*64];
      cv_process(d5, l, mp, i+5); if (i+13 < 32) d5 = ap[(i+13)*64];
      cv_process(d6, l, mp, i+6); if (i+14 < 32) d6 = ap[(i+14)*64];
      cv_process(d7, l, mp, i+7); if (i+15 < 32) d7 = ap[(i+15)*64];
    }
  }
}

// ---- k_attn: block = 64 i-rows x 1024-j kchunk. WhT+fd staged in LDS;
// adj via bitmask (1 word / 32 j, L2-resident). DOUBLE-WIDTH stages vs R0:
// 64 j per stage (2x attn_math, 8 MFMA), 32 barriers instead of 64,
// WhT prefetch distance ~2 substeps (covers L2 latency).
__device__ __forceinline__ void attn_math(unsigned mbits, f32x4 fv0, f32x4 fv1,
    short8 w0, short8 w1, short8 w2, short8 w3,
    float fsrL, float mL, f32x4* acc, float& s0, float& s1){
  const float fv[8] = {fv0[0],fv0[1],fv0[2],fv0[3], fv1[0],fv1[1],fv1[2],fv1[3]};
  float w[8];
  #pragma unroll
  for (int j = 0; j < 8; ++j){
    float x  = fsrL + fv[j];                      // log2 domain
    float tt = fmaxf(x, 0.2f*x);                  // leaky_relu (scale-invariant)
    float e  = __builtin_amdgcn_exp2f(tt - mL);   // v_exp_f32
    w[j] = (mbits & (1u << j)) ? e : 0.0f;        // adj bit
  }
  s0 += (w[0]+w[2]) + (w[4]+w[6]);
  s1 += (w[1]+w[3]) + (w[5]+w[7]);
  short8 af;
  __hip_bfloat162* afp = (__hip_bfloat162*)&af;
  #pragma unroll
  for (int j = 0; j < 4; ++j)
    afp[j] = __float22bfloat162_rn(make_float2(w[2*j], w[2*j+1]));  // v_cvt_pk_bf16_f32
  acc[0] = __builtin_amdgcn_mfma_f32_16x16x32_bf16(af, w0, acc[0], 0,0,0);
  acc[1] = __builtin_amdgcn_mfma_f32_16x16x32_bf16(af, w1, acc[1], 0,0,0);
  acc[2] = __builtin_amdgcn_mfma_f32_16x16x32_bf16(af, w2, acc[2], 0,0,0);
  acc[3] = __builtin_amdgcn_mfma_f32_16x16x32_bf16(af, w3, acc[3], 0,0,0);
}

// Verified layouts (m89/m120): A[m=lane&15][k=(lane>>4)*8+j],
// B[k=(lane>>4)*8+j][n=lane&15], C col=lane&15 row=(lane>>4)*4+reg.
__global__ __launch_bounds__(256, 4) void k_attn(const unsigned* __restrict__ mask,
    const unsigned short* __restrict__ WhT, const float* __restrict__ fs,
    const float* __restrict__ fd, const unsigned* __restrict__ gmax_u,
    float* __restrict__ acc_out, float* __restrict__ s_out){
  __shared__ unsigned short bslab[2][64*PADK2];  // [buf][n][k]  18.4 KB
  __shared__ float fslab[2][64];
  const int t = threadIdx.x, l = t & 63, wv = t >> 6;
  const int g = blockIdx.x & 127;        // 128 groups of 64 i-rows
  const int kchunk = blockIdx.x >> 7;    // 8 k-splits of 1024 j
  const int row = l & 15, quad = l >> 4;
  const int ibase = g*64 + wv*16;
  const int irow  = ibase + row;
  const float gmaxL = __uint_as_float(*gmax_u) - 64.0f;
  const float fsrL  = fs[irow];
  const float xL    = fsrL + gmaxL;
  const float mL    = fmaxf(xL, 0.2f*xL);  // row-max upper bound (leaky monotone)

  const unsigned jbase = (unsigned)kchunk*1024u;
  const unsigned m_off = (unsigned)irow*256u + (jbase >> 5);  // word per 32 j
  const unsigned sg_off = (unsigned)l*8192u + jbase + (unsigned)wv*16u;
  const int      sl_off = l*PADK2 + wv*16;
  const int      qsh    = quad*8;

  f32x4 acc[4];
  #pragma unroll
  for (int nb = 0; nb < 4; ++nb) acc[nb] = (f32x4){0.f,0.f,0.f,0.f};

  // prologue: stage step 0 (64 j) into buf 0; prefetch mask for stages 0,1
  {
    short8 v0 = *(const short8*)(WhT + sg_off);
    short8 v1 = *(const short8*)(WhT + sg_off + 8);
    *(short8*)&bslab[0][sl_off]     = v0;
    *(short8*)&bslab[0][sl_off + 8] = v1;
    if (t < 64) fslab[0][t] = fd[jbase + t];
  }
  unsigned m0a = mask[m_off + 0] >> qsh, m0b = mask[m_off + 1] >> qsh;
  unsigned m1a = mask[m_off + 2] >> qsh, m1b = mask[m_off + 3] >> qsh;

  float s0 = 0.f, s1 = 0.f;
  short8 nw0, nw1; float nf = 0.f;

  #pragma unroll 1
  for (int s = 0; s < 16; s += 2){
    // ---- even stage: consume buf0/m0, stage s+1 -> buf1
    BAR();
    nw0 = *(const short8*)(WhT + sg_off + (s+1)*64);
    nw1 = *(const short8*)(WhT + sg_off + (s+1)*64 + 8);
    if (t < 64) nf = fd[jbase + (s+1)*64 + t];
    {
      f32x4 fv0 = *(const f32x4*)&fslab[0][qsh];
      f32x4 fv1 = *(const f32x4*)&fslab[0][qsh + 4];
      short8 w0 = *(const short8*)&bslab[0][( 0 + row)*PADK2 + qsh];
      short8 w1 = *(const short8*)&bslab[0][(16 + row)*PADK2 + qsh];
      short8 w2 = *(const short8*)&bslab[0][(32 + row)*PADK2 + qsh];
      short8 w3 = *(const short8*)&bslab[0][(48 + row)*PADK2 + qsh];
      attn_math(m0a, fv0, fv1, w0, w1, w2, w3, fsrL, mL, acc, s0, s1);
      fv0 = *(const f32x4*)&fslab[0][32 + qsh];
      fv1 = *(const f32x4*)&fslab[0][32 + qsh + 4];
      w0 = *(const short8*)&bslab[0][( 0 + row)*PADK2 + 32 + qsh];
      w1 = *(const short8*)&bslab[0][(16 + row)*PADK2 + 32 + qsh];
      w2 = *(const short8*)&bslab[0][(32 + row)*PADK2 + 32 + qsh];
      w3 = *(const short8*)&bslab[0][(48 + row)*PADK2 + 32 + qsh];
      attn_math(m0b, fv0, fv1, w0, w1, w2, w3, fsrL, mL, acc, s0, s1);
    }
    if (s + 2 < 16){
      m0a = mask[m_off + (s+2)*2]     >> qsh;
      m0b = mask[m_off + (s+2)*2 + 1] >> qsh;
    }
    *(short8*)&bslab[1][sl_off]     = nw0;
    *(short8*)&bslab[1][sl_off + 8] = nw1;
    if (t < 64) fslab[1][t] = nf;

    // ---- odd stage: consume buf1/m1, stage s+2 -> buf0
    BAR();
    if (s + 2 < 16){
      nw0 = *(const short8*)(WhT + sg_off + (s+2)*64);
      nw1 = *(const short8*)(WhT + sg_off + (s+2)*64 + 8);
      if (t < 64) nf = fd[jbase + (s+2)*64 + t];
    }
    {
      f32x4 fv0 = *(const f32x4*)&fslab[1][qsh];
      f32x4 fv1 = *(const f32x4*)&fslab[1][qsh + 4];
      short8 w0 = *(const short8*)&bslab[1][( 0 + row)*PADK2 + qsh];
      short8 w1 = *(const short8*)&bslab[1][(16 + row)*PADK2 + qsh];
      short8 w2 = *(const short8*)&bslab[1][(32 + row)*PADK2 + qsh];
      short8 w3 = *(const short8*)&bslab[1][(48 + row)*PADK2 + qsh];
      attn_math(m1a, fv0, fv1, w0, w1, w2, w3, fsrL, mL, acc, s0, s1);
      fv0 = *(const f32x4*)&fslab[1][32 + qsh];
      fv1 = *(const f32x4*)&fslab[1][32 + qsh + 4];
      w0 = *(const short8*)&bslab[1][( 0 + row)*PADK2 + 32 + qsh];
      w1 = *(const short8*)&bslab[1][(16 + row)*PADK2 + 32 + qsh];
      w2 = *(const short8*)&bslab[1][(32 + row)*PADK2 + 32 + qsh];
      w3 = *(const short8*)&bslab[1][(48 + row)*PADK2 + 32 + qsh];
      attn_math(m1b, fv0, fv1, w0, w1, w2, w3, fsrL, mL, acc, s0, s1);
    }
    if (s + 3 < 16){
      m1a = mask[m_off + (s+3)*2]     >> qsh;
      m1b = mask[m_off + (s+3)*2 + 1] >> qsh;
    }
    if (s + 2 < 16){
      *(short8*)&bslab[0][sl_off]     = nw0;
      *(short8*)&bslab[0][sl_off + 8] = nw1;
      if (t < 64) fslab[0][t] = nf;
    }
  }

  float sacc = s0 + s1;
  sacc += __shfl_xor(sacc, 16);
  sacc += __shfl_xor(sacc, 32);
  if (l < 16) s_out[kchunk*NN + ibase + l] = sacc;
  float* op = acc_out + ((size_t)kchunk*NN + ibase)*FOUT;
  #pragma unroll
  for (int nb = 0; nb < 4; ++nb)
    #pragma unroll
    for (int r = 0; r < 4; ++r)
      op[(quad*4 + r)*FOUT + nb*16 + row] = acc[nb][r];
}

// ---- k_out: combine 8 split-K partials, normalize, ELU.
__global__ __launch_bounds__(256) void k_out(const float* __restrict__ acc,
    const float* __restrict__ s, float* __restrict__ out){
  const int idx = blockIdx.x*256 + threadIdx.x;   // 524288 total
  const int i = idx >> 6;
  float num = 0.f, den = 0.f;
  #pragma unroll
  for (int ks = 0; ks < 8; ++ks){
    num += acc[idx + (size_t)ks*(NN*FOUT)];
    den += s[i + ks*NN];
  }
  float x = num / den;
  out[idx] = (x > 0.f) ? x : (__expf(x) - 1.0f);
}

extern "C" void kernel_launch(void* const* d_in, const int* in_sizes, int n_in,
                              void* d_out, int out_size, void* d_ws, size_t ws_size,
                              hipStream_t stream){
  const float* h   = (const float*)d_in[0];
  const int*   adj = (const int*)d_in[1];
  const float* W   = (const float*)d_in[2];
  const float* a   = (const float*)d_in[3];
  char* ws = (char*)d_ws;
  // ws: [0,1M) WhT | 1M fs | +32K fd | +64K gmax | [2M,18M) acc x8 |
  //     [20M,+256K) s x8 | [48M,56M) mask (2M words)
  unsigned short* WhT = (unsigned short*)ws;
  float*    fs     = (float*)(ws + (1u<<20));
  float*    fd     = (float*)(ws + (1u<<20) + 32768);
  unsigned* gmax_u = (unsigned*)(ws + (1u<<20) + 65536);
  float*    acc    = (float*)(ws + (2u<<20));
  float*    s_ws   = (float*)(ws + (20u<<20));
  unsigned* mask   = (unsigned*)(ws + (48u<<20));

  (void)hipMemsetAsync(gmax_u, 0, 4, stream);
  k_pm<<<3072, 256, 0, stream>>>(h, W, a, adj, WhT, fs, fd, gmax_u, mask);
  k_attn<<<1024, 256, 0, stream>>>(mask, WhT, fs, fd, gmax_u, acc, s_ws);
  k_out<<<2048, 256, 0, stream>>>(acc, s_ws, (float*)d_out);
}